// Round 6
// baseline (259.224 us; speedup 1.0000x reference)
//
#include <hip/hip_runtime.h>

// ZBL screened repulsion + sorted segment sum.
//   d_in[0] Z int32[500000], d_in[1] Dij fp32[16e6], d_in[2] idx_i int32[16e6] (sorted),
//   d_in[3] idx_j int32[16e6], d_in[4] p, d_in[5] d, d_in[6] c[4], d_in[7] a[4]
// Output: fp32[500000] segment_sum over idx_i.
//
// Round 6: rounds 2/4/5 establish the bound is per-lane address processing of
// divergent gathers (~4.6-5.6 cyc/lane, invariant to occupancy and cache
// path). Two gather streams exist: j (random, irreducible) and i (sorted,
// ~95% redundant within a thread's 16 edges). This round removes the i-side
// lanes: gather zp only at iv[0] and iv[15], select per-edge, rare fallback
// for middle atoms. z8/LDS-pt path deleted (both sides read float zpf).
// j-side keeps the sc0 L1-bypass win from round 5.

#define EPT   16        // edges per thread (16e6 divisible by 16)
#define BLOCK 256
#define MAXZ  95

__device__ __forceinline__ float fast_exp2(float x) {
#if __has_builtin(__builtin_amdgcn_exp2f)
    return __builtin_amdgcn_exp2f(x);   // v_exp_f32
#else
    return exp2f(x);
#endif
}

// Stage: per-atom zp = Z^p float table (2MB, L2-resident).
__global__ void __launch_bounds__(BLOCK) zbl_stage_kernel(
    const int* __restrict__ Z, const float* __restrict__ p,
    float* __restrict__ zpf, int n)
{
    int i = blockIdx.x * BLOCK + threadIdx.x;
    if (i < n) zpf[i] = powf((float)Z[i], p[0]);   // 0^p = 0, correct
}

__global__ void __launch_bounds__(BLOCK) zbl_edge_kernel(
    const float* __restrict__ Dij,
    const int*   __restrict__ idx_i,
    const int*   __restrict__ idx_j,
    const float* __restrict__ zpf,
    const float* __restrict__ dptr,
    const float* __restrict__ c,
    const float* __restrict__ a,
    float*       __restrict__ out,
    long long E)
{
    const long long t    = (long long)blockIdx.x * BLOCK + threadIdx.x;
    const long long base = t * EPT;
    if (base >= E) return;

    const float LOG2E = 1.4426950408889634f;
    const float invd  = 1.0f / dptr[0];
    const float m0 = -a[0] * LOG2E * invd;
    const float m1 = -a[1] * LOG2E * invd;
    const float m2 = -a[2] * LOG2E * invd;
    const float m3 = -a[3] * LOG2E * invd;
    const float c0 = c[0], c1 = c[1], c2 = c[2], c3 = c[3];

    if (base + EPT <= E) {
        // Phase 1: coalesced streams into registers (12 x dwordx4).
        float dv[EPT];
        int   iv[EPT], jv[EPT];
#pragma unroll
        for (int v = 0; v < EPT; v += 4) {
            const float4 dq = *reinterpret_cast<const float4*>(Dij  + base + v);
            const int4   iq = *reinterpret_cast<const int4*>(idx_i + base + v);
            const int4   jq = *reinterpret_cast<const int4*>(idx_j + base + v);
            dv[v] = dq.x; dv[v+1] = dq.y; dv[v+2] = dq.z; dv[v+3] = dq.w;
            iv[v] = iq.x; iv[v+1] = iq.y; iv[v+2] = iq.z; iv[v+3] = iq.w;
            jv[v] = jq.x; jv[v+1] = jq.y; jv[v+2] = jq.z; jv[v+3] = jq.w;
        }
        // Phase 2a: j-gathers bypass L1 (agent scope => sc0 => L2 direct).
        float zpj[EPT];
#pragma unroll
        for (int k = 0; k < EPT; ++k) {
            zpj[k] = __hip_atomic_load(zpf + jv[k], __ATOMIC_RELAXED,
                                       __HIP_MEMORY_SCOPE_AGENT);
        }
        // Phase 2b: i-side — idx_i sorted, so a thread's 16 edges span
        // iv[0]..iv[15]. Gather only the two endpoint atoms; middle atoms
        // (rare: ~8% of threads, few edges each) fall back to a real gather.
        const int   iFirst  = iv[0], iLast = iv[EPT - 1];
        const float zpFirst = zpf[iFirst];
        const float zpLast  = (iLast == iFirst) ? zpFirst : zpf[iLast];
        float zpi[EPT];
#pragma unroll
        for (int k = 0; k < EPT; ++k) {
            zpi[k] = (iv[k] == iFirst) ? zpFirst
                   : (iv[k] == iLast)  ? zpLast
                   : zpf[iv[k]];
        }
        // Phase 3: compute + segmented accumulate (idx_i sorted).
        int   cur = iFirst;
        float acc = 0.0f;
#pragma unroll
        for (int k = 0; k < EPT; ++k) {
            const float tt = dv[k] * (zpi[k] + zpj[k]);
            float v;
            v = c0 * fast_exp2(m0 * tt);
            v = fmaf(c1, fast_exp2(m1 * tt), v);
            v = fmaf(c2, fast_exp2(m2 * tt), v);
            v = fmaf(c3, fast_exp2(m3 * tt), v);
            if (iv[k] != cur) { atomicAdd(out + cur, acc); acc = 0.0f; cur = iv[k]; }
            acc += v;
        }
        atomicAdd(out + cur, acc);
    } else {
        int   cur = idx_i[base];
        float acc = 0.0f;
        for (long long e = base; e < E; ++e) {
            const int   i  = idx_i[e];
            const float zj = __hip_atomic_load(zpf + idx_j[e], __ATOMIC_RELAXED,
                                               __HIP_MEMORY_SCOPE_AGENT);
            const float tt = Dij[e] * (zpf[i] + zj);
            float v;
            v = c0 * fast_exp2(m0 * tt);
            v = fmaf(c1, fast_exp2(m1 * tt), v);
            v = fmaf(c2, fast_exp2(m2 * tt), v);
            v = fmaf(c3, fast_exp2(m3 * tt), v);
            if (i != cur) { atomicAdd(out + cur, acc); acc = 0.0f; cur = i; }
            acc += v;
        }
        atomicAdd(out + cur, acc);
    }
}

extern "C" void kernel_launch(void* const* d_in, const int* in_sizes, int n_in,
                              void* d_out, int out_size, void* d_ws, size_t ws_size,
                              hipStream_t stream)
{
    const int*   Z     = (const int*)  d_in[0];
    const float* Dij   = (const float*)d_in[1];
    const int*   idx_i = (const int*)  d_in[2];
    const int*   idx_j = (const int*)  d_in[3];
    const float* p     = (const float*)d_in[4];
    const float* d     = (const float*)d_in[5];
    const float* c     = (const float*)d_in[6];
    const float* a     = (const float*)d_in[7];
    float*       out   = (float*)d_out;

    const int       nAtoms = in_sizes[0];
    const long long E      = in_sizes[1];

    float* zpf = (float*)d_ws;   // nAtoms floats (2MB)

    // d_out is re-poisoned 0xAA before every timed launch; we need zeros.
    (void)hipMemsetAsync(d_out, 0, (size_t)out_size * sizeof(float), stream);

    zbl_stage_kernel<<<(nAtoms + BLOCK - 1) / BLOCK, BLOCK, 0, stream>>>(Z, p, zpf, nAtoms);

    const long long nThreads = (E + EPT - 1) / EPT;
    const int       nBlocks  = (int)((nThreads + BLOCK - 1) / BLOCK);
    zbl_edge_kernel<<<nBlocks, BLOCK, 0, stream>>>(Dij, idx_i, idx_j, zpf, d, c, a, out, E);
}